// Round 3
// baseline (547.570 us; speedup 1.0000x reference)
//
#include <hip/hip_runtime.h>
#include <hip/hip_bf16.h>

// B=8, T=2048, E=1024 single-head attention, bf16 MFMA pipeline, round 3:
// r2 GEMM core (global_load_lds x16, XOR-swizzled LDS, XCD grid swizzle) plus:
// - V^T written directly by the projection epilogue (transpose kernel removed)
// - softmax fused: QK epilogue writes exp(s) + atomic row sums; PV scales by 1/rowsum
typedef __attribute__((ext_vector_type(8))) short short8;
typedef __attribute__((ext_vector_type(8))) unsigned short ushortx8;
typedef __attribute__((ext_vector_type(4))) unsigned short ushortx4;
typedef __attribute__((ext_vector_type(4))) float floatx4;

#define NB 8
#define NT 2048
#define NE 1024

__device__ __forceinline__ unsigned short f2bf(float f){
  unsigned int u = __builtin_bit_cast(unsigned int, f);
  u += 0x7FFFu + ((u >> 16) & 1u);          // RNE; inputs finite
  return (unsigned short)(u >> 16);
}
__device__ __forceinline__ float bf2f(unsigned short h){
  unsigned int u = ((unsigned int)h) << 16;
  return __builtin_bit_cast(float, u);
}

__device__ __forceinline__ void async16(void* lds, const void* g){
  __builtin_amdgcn_global_load_lds(
      (const __attribute__((address_space(1))) unsigned int*)g,
      (__attribute__((address_space(3))) unsigned int*)lds, 16, 0, 0);
}

// ---------------- fp32 -> bf16 convert, 3 sources ----------------
__global__ __launch_bounds__(256) void cvt3(const float* __restrict__ a0,
                                            const float* __restrict__ a1,
                                            const float* __restrict__ a2,
                                            unsigned short* __restrict__ out,
                                            int n4_per){
  const float* src = blockIdx.y == 0 ? a0 : (blockIdx.y == 1 ? a1 : a2);
  unsigned short* dst = out + (size_t)blockIdx.y * (size_t)n4_per * 4;
  int i = blockIdx.x * 256 + threadIdx.x;
  if (i < n4_per){
    floatx4 f = ((const floatx4*)src)[i];
    ushortx4 o;
    o.x = f2bf(f.x); o.y = f2bf(f.y); o.z = f2bf(f.z); o.w = f2bf(f.w);
    *(ushortx4*)(dst + (size_t)i * 4) = o;
  }
}

// ---------------- mask [2048][2048] int32 -> bitmask (512 KB) ----------------
__global__ __launch_bounds__(256) void pack_mask(const int* __restrict__ m,
                                                 unsigned long long* __restrict__ bits){
  int t = blockIdx.x * 256 + threadIdx.x;          // 65536 words
  const int4* p = (const int4*)(m + (size_t)t * 64);
  unsigned long long w = 0;
  #pragma unroll
  for (int jj = 0; jj < 16; jj++){
    int4 v = p[jj];
    w |= (unsigned long long)(v.x != 0) << (jj * 4 + 0);
    w |= (unsigned long long)(v.y != 0) << (jj * 4 + 1);
    w |= (unsigned long long)(v.z != 0) << (jj * 4 + 2);
    w |= (unsigned long long)(v.w != 0) << (jj * 4 + 3);
  }
  bits[t] = w;
}

// ---------------- zero the rowsum accumulator (re-poisoned each call) ----------------
__global__ __launch_bounds__(256) void zero_rs(float* __restrict__ p){
  p[blockIdx.x * 256 + threadIdx.x] = 0.0f;
}

// ---------------- NT GEMM: C[m,n] = sum_k A[m,k]*B[n,k], all bf16 in ----------------
// Tile 128x128, BK=64, 4 waves (each 64x64 = 4x4 of 16x16x32 MFMAs).
// Staging: global_load_lds dwordx4; LDS slot f(row,c) = row*8 + (c ^ (row&7)) (16B chunks).
// Grid: 1-D, XCD-swizzled: all gx n-tiles of one A-strip land consecutively on one XCD.
// EPI 0: projections — z<2 store bf16; z==2 store transposed (V^T) via LDS bounce.
// EPI 1: QK — p = maskbit ? exp(v/32) : 0, store bf16, atomicAdd row sums.
// EPI 2: PV — store fp32 scaled by 1/rowsum[row].
template<int EPI>
__global__ __launch_bounds__(256) void gemm_nt(
    const unsigned short* __restrict__ A, long strideA,
    const unsigned short* __restrict__ B, long strideB,
    void* __restrict__ Out, long strideOutBytes,
    const unsigned long long* __restrict__ mbits,
    float* __restrict__ rowsum,
    int K, int gx, int gy)
{
  constexpr int SMEM_SHORTS = (EPI == 0) ? 17408 : 16384;   // EPI0: 128x136 epi buffer
  __shared__ __attribute__((aligned(16))) unsigned short smem[SMEM_SHORTS];
  unsigned short* As = smem;                                 // 128*64
  unsigned short* Bs = smem + 8192;                          // 128*64
  const int tid = threadIdx.x;
  const int lane = tid & 63, wave = tid >> 6;

  // XCD-aware decode: L%8 = XCD; all gx x-tiles of one (y,z) strip on one XCD.
  int L = blockIdx.x;
  int xcd = L & 7, t = L >> 3;
  int x = t % gx;
  int strip = xcd + ((t / gx) << 3);
  int y = strip % gy, z = strip / gy;
  const int m0 = y << 7, n0 = x << 7;
  const int Nn = gx << 7;

  const unsigned short* Az = A + (size_t)z * strideA;
  const unsigned short* Bz = B + (size_t)z * strideB;

  // Staging: 1024 slots of 16 B per tile; inverse swizzle row=s>>3, chunk=(s&7)^(row&7).
  const char* gA[4]; const char* gB[4]; int lo[4];
  {
    int s0 = (wave << 8) + lane;
    #pragma unroll
    for (int i = 0; i < 4; i++){
      int s = s0 + (i << 6);
      int row = s >> 3;
      int c = (s & 7) ^ (row & 7);
      lo[i] = s << 4;
      gA[i] = (const char*)(Az + (size_t)(m0 + row) * K) + (c << 4);
      gB[i] = (const char*)(Bz + (size_t)(n0 + row) * K) + (c << 4);
    }
  }
  char* AsB = (char*)As;
  char* BsB = (char*)Bs;

  const int lm = lane & 15, qd = lane >> 4;
  const int wr = (wave >> 1) << 6, wc = (wave & 1) << 6;
  const int sw = lm & 7;
  const char* aB0 = AsB + (wr + lm) * 128 + ((qd ^ sw) << 4);
  const char* aB1 = AsB + (wr + lm) * 128 + (((4 + qd) ^ sw) << 4);
  const char* bB0 = BsB + (wc + lm) * 128 + ((qd ^ sw) << 4);
  const char* bB1 = BsB + (wc + lm) * 128 + (((4 + qd) ^ sw) << 4);

  floatx4 acc[4][4];
  floatx4 zero4 = {0.f, 0.f, 0.f, 0.f};
  #pragma unroll
  for (int a = 0; a < 4; a++)
    #pragma unroll
    for (int b = 0; b < 4; b++) acc[a][b] = zero4;

  for (int kk = 0; kk < K; kk += 64){
    #pragma unroll
    for (int i = 0; i < 4; i++){
      async16(AsB + lo[i], gA[i]);
      async16(BsB + lo[i], gB[i]);
      gA[i] += 128; gB[i] += 128;
    }
    __syncthreads();

    short8 a0[4], a1[4], b0[4], b1[4];
    #pragma unroll
    for (int mi = 0; mi < 4; mi++){
      a0[mi] = *(const short8*)(aB0 + mi * 2048);
      a1[mi] = *(const short8*)(aB1 + mi * 2048);
    }
    #pragma unroll
    for (int ni = 0; ni < 4; ni++){
      b0[ni] = *(const short8*)(bB0 + ni * 2048);
      b1[ni] = *(const short8*)(bB1 + ni * 2048);
    }
    #pragma unroll
    for (int mi = 0; mi < 4; mi++)
      #pragma unroll
      for (int ni = 0; ni < 4; ni++)
        acc[mi][ni] = __builtin_amdgcn_mfma_f32_16x16x32_bf16(a0[mi], b0[ni], acc[mi][ni], 0, 0, 0);
    #pragma unroll
    for (int mi = 0; mi < 4; mi++)
      #pragma unroll
      for (int ni = 0; ni < 4; ni++)
        acc[mi][ni] = __builtin_amdgcn_mfma_f32_16x16x32_bf16(a1[mi], b1[ni], acc[mi][ni], 0, 0, 0);
    __syncthreads();
  }

  // Epilogues. C/D layout: col = lane&15, row = (lane>>4)*4 + i  (m89/m91).
  char* OutZ = (char*)Out + (size_t)z * strideOutBytes;
  if constexpr (EPI == 0){
    if (z < 2){
      #pragma unroll
      for (int mi = 0; mi < 4; mi++)
        #pragma unroll
        for (int i = 0; i < 4; i++){
          int row = m0 + wr + mi * 16 + qd * 4 + i;
          #pragma unroll
          for (int ni = 0; ni < 4; ni++)
            ((unsigned short*)OutZ)[(size_t)row * Nn + wc + n0 + ni * 16 + lm] =
                f2bf(acc[mi][ni][i]);
        }
    } else {
      // V^T: bounce the 128x128 tile through LDS transposed (pad stride 136).
      #pragma unroll
      for (int mi = 0; mi < 4; mi++)
        #pragma unroll
        for (int ni = 0; ni < 4; ni++)
          #pragma unroll
          for (int i = 0; i < 4; i++)
            smem[(wc + ni * 16 + lm) * 136 + (wr + mi * 16 + qd * 4 + i)] =
                f2bf(acc[mi][ni][i]);
      __syncthreads();
      int c = tid >> 1, half = tid & 1;               // V^T row n0+c, t-half
      int b = m0 >> 11;
      unsigned short* dst = (unsigned short*)OutZ + (size_t)b * NE * NT +
                            (size_t)(n0 + c) * NT + (m0 & 2047) + half * 64;
      const unsigned short* srcp = smem + c * 136 + half * 64;
      #pragma unroll
      for (int j = 0; j < 8; j++)
        *(ushortx8*)(dst + j * 8) = *(const ushortx8*)(srcp + j * 8);
    }
  } else if constexpr (EPI == 1){
    int wcol = (n0 + wc) >> 6;
    #pragma unroll
    for (int mi = 0; mi < 4; mi++){
      #pragma unroll
      for (int i = 0; i < 4; i++){
        int row = m0 + wr + mi * 16 + qd * 4 + i;
        unsigned long long w = mbits[(size_t)row * (NT / 64) + wcol];
        unsigned short* po = (unsigned short*)OutZ + (size_t)row * Nn + n0 + wc;
        float partial = 0.0f;
        #pragma unroll
        for (int ni = 0; ni < 4; ni++){
          float p = ((w >> (ni * 16 + lm)) & 1ull)
                        ? __expf(acc[mi][ni][i] * 0.03125f) : 0.0f;
          unsigned short h = f2bf(p);
          partial += bf2f(h);                     // sum what PV will actually read
          po[ni * 16 + lm] = h;
        }
        partial += __shfl_xor(partial, 1, 64);
        partial += __shfl_xor(partial, 2, 64);
        partial += __shfl_xor(partial, 4, 64);
        partial += __shfl_xor(partial, 8, 64);
        if (lm == 0) atomicAdd(&rowsum[(size_t)z * NT + row], partial);
      }
    }
  } else {
    #pragma unroll
    for (int mi = 0; mi < 4; mi++){
      #pragma unroll
      for (int i = 0; i < 4; i++){
        int row = m0 + wr + mi * 16 + qd * 4 + i;
        float inv = 1.0f / rowsum[(size_t)z * NT + row];
        #pragma unroll
        for (int ni = 0; ni < 4; ni++)
          ((float*)OutZ)[(size_t)row * Nn + n0 + wc + ni * 16 + lm] =
              acc[mi][ni][i] * inv;
      }
    }
  }
}

extern "C" void kernel_launch(void* const* d_in, const int* in_sizes, int n_in,
                              void* d_out, int out_size, void* d_ws, size_t ws_size,
                              hipStream_t stream){
  const float* q  = (const float*)d_in[0];
  const float* k  = (const float*)d_in[1];
  const float* v  = (const float*)d_in[2];
  const int* mask = (const int*)d_in[3];
  const float* Wq = (const float*)d_in[4];
  const float* Wk = (const float*)d_in[5];
  const float* Wv = (const float*)d_in[6];

  const size_t BTE = (size_t)NB * NT * NE;     // 16,777,216
  unsigned short* ws   = (unsigned short*)d_ws;
  // [0,B): Qproj  [B,2B): Kproj  [2B,3B): V^T (written directly by proj epi)
  unsigned short* QKVp = ws;
  unsigned short* Qp   = QKVp;
  unsigned short* Kp   = QKVp + BTE;
  unsigned short* VpT  = QKVp + 2 * BTE;
  // [3B,6B): bf16 inputs q,k,v (dead after proj); Sb overlays [3B,5B) afterwards.
  unsigned short* Qin  = ws + 3 * BTE;
  unsigned short* Sb   = ws + 3 * BTE;
  // [6B, ...): weights bf16, bitmask, rowsum
  unsigned short* Wb   = ws + 6 * BTE;                         // [3][E][E]
  unsigned long long* mbits = (unsigned long long*)(Wb + (size_t)3 * NE * NE);
  float* rowsum = (float*)(mbits + (size_t)NT * NT / 64);      // [8][2048]

  // 1) fp32 -> bf16 inputs; 2) weights; 3) mask bits; 4) zero rowsum
  cvt3<<<dim3(16384, 3), 256, 0, stream>>>(q, k, v, Qin, (int)(BTE / 4));
  cvt3<<<dim3(1024, 3), 256, 0, stream>>>(Wq, Wk, Wv, Wb, NE * NE / 4);
  pack_mask<<<256, 256, 0, stream>>>(mask, mbits);
  zero_rs<<<NB * NT / 256, 256, 0, stream>>>(rowsum);

  // 5) projections (z=0:Q, 1:K, 2:V->V^T); gx=8, gy=128, gz=3
  gemm_nt<0><<<3072, 256, 0, stream>>>(
      Qin, (long)BTE, Wb, (long)NE * NE,
      QKVp, (long)BTE * 2, nullptr, nullptr, NE, 8, 128);

  // 6) P_unnorm = mask ? exp(QK^T/32) : 0  (+ row sums); gx=16, gy=16, gz=8
  gemm_nt<1><<<2048, 256, 0, stream>>>(
      Qp, (long)NT * NE, Kp, (long)NT * NE,
      Sb, (long)NT * NT * 2, mbits, rowsum, NE, 16, 16);

  // 7) O = (P_unnorm @ V) / rowsum; gx=8, gy=16, gz=8, fp32 out
  gemm_nt<2><<<1024, 256, 0, stream>>>(
      Sb, (long)NT * NT, VpT, (long)NE * NT,
      d_out, (long)NT * NE * 4, nullptr, rowsum, NT, 8, 16);
}